// Round 5
// baseline (3300.457 us; speedup 1.0000x reference)
//
#include <hip/hip_runtime.h>

#define T_DIM 512
#define N_DIM 1024
#define K_DIM 2048

typedef _Float16 f16;
typedef _Float16 f16x4 __attribute__((ext_vector_type(4)));
typedef _Float16 f16x8 __attribute__((ext_vector_type(8)));
typedef float f32x16 __attribute__((ext_vector_type(16)));
typedef __attribute__((address_space(1))) const unsigned int GU32;
typedef __attribute__((address_space(3))) unsigned int LU32;

__device__ __forceinline__ void gload16(const void* g, void* l) {
  __builtin_amdgcn_global_load_lds((GU32*)g, (LU32*)l, 16, 0, 0);
}

// ---------------------------------------------------------------------------
// Kernel 0: pre-split w into f16 {w0, w1} laid out as the GEMM's A-LDS image:
// wimg[nt(4)][k16(128)][ (lhi*2+c)*256 + row ] * 8 f16   (16 KB per (nt,k16))
//   v = 64*w ; w0 = f16(v) ; w1 = f16((v - w0) * 4096)
// ---------------------------------------------------------------------------
__global__ __launch_bounds__(256) void presplit_w(const float* __restrict__ w,
                                                  f16* __restrict__ wimg) {
  const int gid = blockIdx.x * 256 + threadIdx.x;  // 262144
  const int ko = gid >> 10;   // k-octet 0..255
  const int n = gid & 1023;
  const float* src = w + (size_t)n * K_DIM + (ko << 3);
  const float4 v0 = *(const float4*)src;
  const float4 v1 = *(const float4*)(src + 4);
  const float vv[8] = {v0.x, v0.y, v0.z, v0.w, v1.x, v1.y, v1.z, v1.w};
  f16x8 h0, h1;
#pragma unroll
  for (int q = 0; q < 8; ++q) {
    const float v = vv[q] * 64.f;
    const f16 a = (f16)v;
    h0[q] = a;
    h1[q] = (f16)((v - (float)a) * 4096.f);
  }
  const int nt = n >> 8, row = n & 255;
  const int k16 = ko >> 1, lhi = ko & 1;
  f16* blk = wimg + (size_t)(nt * 128 + k16) * 8192;
  *(f16x8*)&blk[(((lhi << 1) | 0) * 256 + row) * 8] = h0;
  *(f16x8*)&blk[(((lhi << 1) | 1) * 256 + row) * 8] = h1;
}

// ---------------------------------------------------------------------------
// Kernel 1: z[b][t][n] = sum_i w[n][i]*x[b][i][t]  (z into d_out, [B][T][N])
// Block 256(n) x 128(t), 8 waves (4n x 2t) of 64x64, K-step 16, double-buffer.
// A staged via global_load_lds from pre-split wimg; x split in-register.
// acc0 += w0*x0 ; acc1 += w0*x1 + w1*x0 ; z = acc0/64 + acc1/(64*4096).
// __launch_bounds__(512, 1): 1 wg/CU -> 2 waves/SIMD -> 256-VGPR budget.
// (512, 2) spilled: 4 waves/SIMD caps VGPR at 128 < ~190 live regs. [R4 bug]
// ---------------------------------------------------------------------------
__global__ __launch_bounds__(512, 1) void gemm_split(const float* __restrict__ x,
                                                     const f16* __restrict__ wimg,
                                                     float* __restrict__ z) {
  const int p = blockIdx.x;
  const int lg = ((p & 7) << 7) | (p >> 3);  // bijective XCD swizzle (1024 % 8 == 0)
  const int nt = lg & 3;
  const int tt = (lg >> 2) & 3;
  const int b = lg >> 4;
  const int n0 = nt << 8, t0 = tt << 7;

  __shared__ f16 sA[2][8192];  // [buf][(lhi*2+c)*256 + row][8]  16 KB/buf
  __shared__ f16 sB[2][4096];  // [buf][(lhi*2+c)*128 + t][8]     8 KB/buf

  const int tid = threadIdx.x;
  const int lane = tid & 63;
  const int l31 = lane & 31, lhi = lane >> 5;
  const int wv = tid >> 6;   // 0..7
  const int wm = wv >> 1;    // 0..3 (n)
  const int wt = wv & 1;     // 0..1 (t)

  // x staging role: tcol 0..127, kq 0..3 (4 k-rows each)
  const int tcol = tid & 127, kq = tid >> 7;
  const float* pX = x + (size_t)b * (K_DIM * T_DIM) + (size_t)(kq << 2) * T_DIM + t0 + tcol;

  const f16* wbase = wimg + (size_t)nt * (128 * 8192);
  const int chunkelem = (wv * 2) * 512 + lane * 8;  // two 1KB chunks per wave

  // fragment read offsets (f16 elements)
  const int aoff0 = (((lhi << 1) | 0) * 256 + wm * 64 + l31) * 8;
  const int aoff1 = (((lhi << 1) | 1) * 256 + wm * 64 + l31) * 8;
  const int boff0 = (((lhi << 1) | 0) * 128 + wt * 64 + l31) * 8;
  const int boff1 = (((lhi << 1) | 1) * 128 + wt * 64 + l31) * 8;

  // x staging write offsets
  const int bwl = kq >> 1;
  const int bwq = (kq & 1) * 4;
  const int bso0 = (((bwl << 1) | 0) * 128 + tcol) * 8 + bwq;
  const int bso1 = (((bwl << 1) | 1) * 128 + tcol) * 8 + bwq;

  f32x16 acc0[2][2], acc1[2][2];
#pragma unroll
  for (int i = 0; i < 2; ++i)
#pragma unroll
    for (int j = 0; j < 2; ++j)
#pragma unroll
      for (int r = 0; r < 16; ++r) {
        acc0[i][j][r] = 0.f;
        acc1[i][j][r] = 0.f;
      }

  float xv0, xv1, xv2, xv3;

#define LOADX(IT)                                                       \
  {                                                                     \
    const size_t ro = (size_t)((IT) * 16) * T_DIM;                      \
    xv0 = pX[ro];                                                       \
    xv1 = pX[ro + T_DIM];                                               \
    xv2 = pX[ro + 2 * T_DIM];                                           \
    xv3 = pX[ro + 3 * T_DIM];                                           \
  }

#define STAGE(BUF, IT)                                                  \
  {                                                                     \
    const f16* ws = wbase + (size_t)(IT) * 8192 + chunkelem;            \
    gload16(ws, &sA[BUF][chunkelem]);                                   \
    gload16(ws + 512, &sA[BUF][chunkelem + 512]);                       \
    f16x4 g0, g1;                                                       \
    { const float v = xv0; const f16 a = (f16)v; g0[0] = a; g1[0] = (f16)((v - (float)a) * 4096.f); } \
    { const float v = xv1; const f16 a = (f16)v; g0[1] = a; g1[1] = (f16)((v - (float)a) * 4096.f); } \
    { const float v = xv2; const f16 a = (f16)v; g0[2] = a; g1[2] = (f16)((v - (float)a) * 4096.f); } \
    { const float v = xv3; const f16 a = (f16)v; g0[3] = a; g1[3] = (f16)((v - (float)a) * 4096.f); } \
    *(f16x4*)&sB[BUF][bso0] = g0;                                       \
    *(f16x4*)&sB[BUF][bso1] = g1;                                       \
  }

#define COMPUTE(BUF)                                                    \
  {                                                                     \
    f16x8 a0[2], a1[2], b0[2], b1[2];                                   \
    a0[0] = *(const f16x8*)&sA[BUF][aoff0];                             \
    a0[1] = *(const f16x8*)&sA[BUF][aoff0 + 32 * 8];                    \
    a1[0] = *(const f16x8*)&sA[BUF][aoff1];                             \
    a1[1] = *(const f16x8*)&sA[BUF][aoff1 + 32 * 8];                    \
    b0[0] = *(const f16x8*)&sB[BUF][boff0];                             \
    b0[1] = *(const f16x8*)&sB[BUF][boff0 + 32 * 8];                    \
    b1[0] = *(const f16x8*)&sB[BUF][boff1];                             \
    b1[1] = *(const f16x8*)&sB[BUF][boff1 + 32 * 8];                    \
    _Pragma("unroll")                                                   \
    for (int f = 0; f < 2; ++f)                                         \
      _Pragma("unroll")                                                 \
      for (int g = 0; g < 2; ++g) {                                     \
        acc0[f][g] = __builtin_amdgcn_mfma_f32_32x32x16_f16(a0[f], b0[g], acc0[f][g], 0, 0, 0); \
        acc1[f][g] = __builtin_amdgcn_mfma_f32_32x32x16_f16(a0[f], b1[g], acc1[f][g], 0, 0, 0); \
        acc1[f][g] = __builtin_amdgcn_mfma_f32_32x32x16_f16(a1[f], b0[g], acc1[f][g], 0, 0, 0); \
      }                                                                 \
  }

  // prologue
  LOADX(0);
  STAGE(0, 0);
  LOADX(1);
  __syncthreads();

  int cur = 0;
  for (int it = 0; it < 128; ++it) {
    if (it < 127) STAGE(cur ^ 1, it + 1);
    if (it < 126) LOADX(it + 2);
    if (cur == 0) {
      COMPUTE(0);
    } else {
      COMPUTE(1);
    }
    __syncthreads();
    cur ^= 1;
  }

#undef LOADX
#undef STAGE
#undef COMPUTE

  // epilogue: z = acc0/64 + acc1/(64*4096), stored z[t][n]
  float* zb = z + (size_t)b * T_DIM * N_DIM;
  const float C0 = 0.015625f;
  const float C1 = 3.814697265625e-06f;
#pragma unroll
  for (int f = 0; f < 2; ++f)
#pragma unroll
    for (int g = 0; g < 2; ++g) {
      const int t = t0 + wt * 64 + g * 32 + l31;
      float* orow = zb + (size_t)t * N_DIM + n0 + wm * 64 + f * 32 + lhi * 4;
#pragma unroll
      for (int q = 0; q < 4; ++q) {
        float4 o;
        o.x = acc0[f][g][4 * q + 0] * C0 + acc1[f][g][4 * q + 0] * C1;
        o.y = acc0[f][g][4 * q + 1] * C0 + acc1[f][g][4 * q + 1] * C1;
        o.z = acc0[f][g][4 * q + 2] * C0 + acc1[f][g][4 * q + 2] * C1;
        o.w = acc0[f][g][4 * q + 3] * C0 + acc1[f][g][4 * q + 3] * C1;
        *(float4*)(orow + q * 8) = o;
      }
    }
}

// ---------------------------------------------------------------------------
// Kernel 2: sequential CUBA-KWTA recurrence, ballot-based spike count.
// ---------------------------------------------------------------------------
__global__ __launch_bounds__(256) void kwta_scan(const float* __restrict__ z,
                                                 const float* __restrict__ se,
                                                 unsigned int* __restrict__ bits) {
  const int b = blockIdx.x;
  const int tid = threadIdx.x;
  const int lane = tid & 63;
  const int wid = tid >> 6;

  float a = se[0];
  a = fminf(fmaxf(a, 0.f), 1.f);
  const float ap1 = 1.f + a;
  const float RB = 0.8046875f;  // TH*(N-2K)/N/WS exact

  __shared__ float part[2][4];

  const float* zb = z + (size_t)b * T_DIM * N_DIM + tid * 4;
  unsigned int* gb = bits + (size_t)b * 16 * N_DIM + tid * 4;

  float4 r0 = *(const float4*)(zb);
  float4 r1 = *(const float4*)(zb + 1 * N_DIM);
  float4 r2 = *(const float4*)(zb + 2 * N_DIM);
  float4 r3 = *(const float4*)(zb + 3 * N_DIM);
  float4 r4 = *(const float4*)(zb + 4 * N_DIM);
  float4 r5 = *(const float4*)(zb + 5 * N_DIM);
  float4 r6 = *(const float4*)(zb + 6 * N_DIM);
  float4 r7 = *(const float4*)(zb + 7 * N_DIM);

  float u0 = 0.f, u1 = 0.f, u2 = 0.f, u3 = 0.f;
  float v0 = 0.f, v1 = 0.f, v2 = 0.f, v3 = 0.f;
  float s0 = 0.f, s1 = 0.f, s2 = 0.f, s3 = 0.f;
  float S = 0.f;
  unsigned int c0 = 0, c1 = 0, c2 = 0, c3 = 0;

#define NEU(U, V, SV, C, ZV)                            \
  {                                                     \
    const float fb  = fmaf(ap1, SV, -S) + RB;           \
    const float inp = ZV + fb;                          \
    U = fmaf(0.75f, U, inp);                            \
    V = fmaf(0.9f, V, U);                               \
    const bool sp = (V >= 1.0f);                        \
    SV = sp ? 1.0f : 0.0f;                              \
    V  = sp ? 0.0f : V;                                 \
    C |= ((unsigned int)sp) << (t & 31);                \
    msum += __popcll(__ballot(sp));                     \
  }

#define STEP(KK, RQ)                                                    \
  {                                                                     \
    const int t = tbase + KK;                                           \
    const float4 z4 = RQ;                                               \
    int tn = t + 8;                                                     \
    if (tn > 511) tn = 511;                                             \
    RQ = *(const float4*)(zb + (size_t)tn * N_DIM);                     \
    int msum = 0;                                                       \
    NEU(u0, v0, s0, c0, z4.x)                                           \
    NEU(u1, v1, s1, c1, z4.y)                                           \
    NEU(u2, v2, s2, c2, z4.z)                                           \
    NEU(u3, v3, s3, c3, z4.w)                                           \
    if (lane == 0) part[t & 1][wid] = (float)msum;                      \
    __syncthreads();                                                    \
    S = (part[t & 1][0] + part[t & 1][1]) +                             \
        (part[t & 1][2] + part[t & 1][3]);                              \
    if ((t & 31) == 31) {                                               \
      *(uint4*)(gb + (size_t)(t >> 5) * N_DIM) =                        \
          make_uint4(c0, c1, c2, c3);                                   \
      c0 = c1 = c2 = c3 = 0;                                            \
    }                                                                   \
  }

  for (int tbase = 0; tbase < T_DIM; tbase += 8) {
    STEP(0, r0)
    STEP(1, r1)
    STEP(2, r2)
    STEP(3, r3)
    STEP(4, r4)
    STEP(5, r5)
    STEP(6, r6)
    STEP(7, r7)
  }
#undef STEP
#undef NEU
}

// ---------------------------------------------------------------------------
// Kernel 3: expand bits -> out[b][n][t] fp32 with 1-step delay shift.
// ---------------------------------------------------------------------------
__global__ __launch_bounds__(256) void expand_out(const unsigned int* __restrict__ bits,
                                                  float* __restrict__ out) {
  const int gid = blockIdx.x * 256 + threadIdx.x;
  const int l = gid & 63;
  const int row = gid >> 6;
  const int b = row >> 10;
  const int n = row & 1023;
  const unsigned int* r = bits + (size_t)b * 16 * N_DIM + n;

  unsigned int byte;
  if (l == 0) {
    byte = (r[0] << 1) & 0xFFu;
  } else {
    const int src = 8 * l - 1;
    const int w0 = src >> 5;
    const unsigned int lo = r[(size_t)w0 * N_DIM];
    const unsigned int hi = (w0 < 15) ? r[(size_t)(w0 + 1) * N_DIM] : 0u;
    const unsigned long long comb = ((unsigned long long)hi << 32) | (unsigned long long)lo;
    byte = (unsigned int)(comb >> (src & 31)) & 0xFFu;
  }

  float f[8];
#pragma unroll
  for (int k = 0; k < 8; ++k) f[k] = (float)((byte >> k) & 1u);

  float* o = out + ((size_t)row << 9) + (l << 3);
  *reinterpret_cast<float4*>(o)     = make_float4(f[0], f[1], f[2], f[3]);
  *reinterpret_cast<float4*>(o + 4) = make_float4(f[4], f[5], f[6], f[7]);
}

// ---------------------------------------------------------------------------
extern "C" void kernel_launch(void* const* d_in, const int* in_sizes, int n_in,
                              void* d_out, int out_size, void* d_ws, size_t ws_size,
                              hipStream_t stream) {
  const float* x  = (const float*)d_in[0];   // [64][2048][512]
  const float* w  = (const float*)d_in[1];   // [1024][2048]
  const float* se = (const float*)d_in[2];   // [1]
  float* out = (float*)d_out;                // [64][1024][512] fp32

  // wimg occupies d_ws[0, 8MB); bits reuses d_ws[0, 4MB) AFTER gemm (wimg dead)
  f16* wimg = (f16*)d_ws;
  unsigned int* bits = (unsigned int*)d_ws;

  presplit_w<<<1024, 256, 0, stream>>>(w, wimg);
  gemm_split<<<1024, 512, 0, stream>>>(x, wimg, out);
  kwta_scan<<<64, 256, 0, stream>>>(out, se, bits);
  expand_out<<<16384, 256, 0, stream>>>(bits, out);
}

// Round 7
// 2716.902 us; speedup vs baseline: 1.2148x; 1.2148x over previous
//
#include <hip/hip_runtime.h>

#define T_DIM 512
#define N_DIM 1024
#define K_DIM 2048

typedef _Float16 f16;
typedef _Float16 f16x8 __attribute__((ext_vector_type(8)));
typedef float f32x16 __attribute__((ext_vector_type(16)));
typedef __attribute__((address_space(1))) const unsigned int GU32;
typedef __attribute__((address_space(3))) unsigned int LU32;

__device__ __forceinline__ void gload16(const void* g, void* l) {
  __builtin_amdgcn_global_load_lds((GU32*)g, (LU32*)l, 16, 0, 0);
}

// ---------------------------------------------------------------------------
// Kernel 0: pre-split w into f16 {w0, w1} laid out as the GEMM's A-LDS image:
// wimg[nt(4)][k16(128)][ (lhi*2+c)*256 + row ] * 8 f16   (16 KB per (nt,k16))
//   v = 64*w ; w0 = f16(v) ; w1 = f16((v - w0) * 4096)
// ---------------------------------------------------------------------------
__global__ __launch_bounds__(256) void presplit_w(const float* __restrict__ w,
                                                  f16* __restrict__ wimg) {
  const int gid = blockIdx.x * 256 + threadIdx.x;  // 262144
  const int ko = gid >> 10;   // k-octet 0..255
  const int n = gid & 1023;
  const float* src = w + (size_t)n * K_DIM + (ko << 3);
  const float4 v0 = *(const float4*)src;
  const float4 v1 = *(const float4*)(src + 4);
  const float vv[8] = {v0.x, v0.y, v0.z, v0.w, v1.x, v1.y, v1.z, v1.w};
  f16x8 h0, h1;
#pragma unroll
  for (int q = 0; q < 8; ++q) {
    const float v = vv[q] * 64.f;
    const f16 a = (f16)v;
    h0[q] = a;
    h1[q] = (f16)((v - (float)a) * 4096.f);
  }
  const int nt = n >> 8, row = n & 255;
  const int k16 = ko >> 1, lhi = ko & 1;
  f16* blk = wimg + (size_t)(nt * 128 + k16) * 8192;
  *(f16x8*)&blk[(((lhi << 1) | 0) * 256 + row) * 8] = h0;
  *(f16x8*)&blk[(((lhi << 1) | 1) * 256 + row) * 8] = h1;
}

// ---------------------------------------------------------------------------
// Kernel 1: z[b][t][n] = sum_i w[n][i]*x[b][i][t]  (z into d_out, [B][T][N])
// Block 256(n) x 128(t), 4 waves (2n x 2t), wave tile 128x64 = (4,2) frags.
// 1 wave/SIMD (amdgpu_waves_per_eu(1,1)): 512-reg budget, demand ~340 -> no
// spill (R3-R5 spilled: acc128+arch~150 > 256 @2 waves/SIMD).
// A staged via global_load_lds from presplit wimg; x split in-register.
// acc0 += w0*x0 ; acc1 += w0*x1 + w1*x0 ; z = acc0/64 + acc1/(64*4096).
// R6 BUG FIX: sB was [2][2048]; layout needs 4 slots x 128 t x 8 f16 = 4096
// f16 per buffer -> OOB writes corrupted buffer 1 (absmax 1.0). Now [2][4096].
// ---------------------------------------------------------------------------
__global__ __launch_bounds__(256) __attribute__((amdgpu_waves_per_eu(1, 1)))
void gemm_split(const float* __restrict__ x,
                const f16* __restrict__ wimg,
                float* __restrict__ z) {
  const int p = blockIdx.x;
  const int lg = ((p & 7) << 7) | (p >> 3);  // bijective XCD swizzle (1024%8==0)
  const int nt = lg & 3;
  const int tt = (lg >> 2) & 3;
  const int b = lg >> 4;
  const int n0 = nt << 8, t0 = tt << 7;

  __shared__ f16 sA[2][8192];  // [(lhi*2+c)*256 + row]*8   16 KB/buf
  __shared__ f16 sB[2][4096];  // [(lhi*2+c)*128 + t]*8      8 KB/buf

  const int tid = threadIdx.x;
  const int lane = tid & 63;
  const int l31 = lane & 31, lhi = lane >> 5;
  const int wv = tid >> 6;   // 0..3
  const int wm = wv >> 1;    // 0..1 (n)
  const int wt = wv & 1;     // 0..1 (t)

  // x staging: tcol 0..127, kh 0..1 (8 k each)
  const int tcol = tid & 127, kh = tid >> 7;
  const float* pX = x + (size_t)b * (K_DIM * T_DIM) + (size_t)(kh * 8) * T_DIM + t0 + tcol;

  const f16* wbase = wimg + (size_t)nt * (128 * 8192);
  const int dmaoff = tid * 8;  // f16 elems; per-thread 4 chunks of 16B

  // fragment read offsets (f16 elems); +2048 elems switches comp c=0 -> c=1 (A)
  const int aO = ((lhi << 1) * 256 + wm * 128 + l31) * 8;
  const int bO = ((lhi << 1) * 128 + wt * 64 + l31) * 8;

  // x staging write offsets
  const int xo0 = (((kh << 1) | 0) * 128 + tcol) * 8;
  const int xo1 = (((kh << 1) | 1) * 128 + tcol) * 8;

  f32x16 acc0[4][2], acc1[4][2];
#pragma unroll
  for (int i = 0; i < 4; ++i)
#pragma unroll
    for (int j = 0; j < 2; ++j)
#pragma unroll
      for (int r = 0; r < 16; ++r) {
        acc0[i][j][r] = 0.f;
        acc1[i][j][r] = 0.f;
      }

  float xv0, xv1, xv2, xv3, xv4, xv5, xv6, xv7;

#define LOADX(IT)                                                       \
  {                                                                     \
    const float* px = pX + (size_t)((IT) * 16) * T_DIM;                 \
    xv0 = px[0];                                                        \
    xv1 = px[1 * T_DIM];                                                \
    xv2 = px[2 * T_DIM];                                                \
    xv3 = px[3 * T_DIM];                                                \
    xv4 = px[4 * T_DIM];                                                \
    xv5 = px[5 * T_DIM];                                                \
    xv6 = px[6 * T_DIM];                                                \
    xv7 = px[7 * T_DIM];                                                \
  }

#define STAGE(BUF, IT)                                                  \
  {                                                                     \
    const f16* ws = wbase + (size_t)(IT) * 8192;                        \
    gload16(ws + dmaoff, &sA[BUF][dmaoff]);                             \
    gload16(ws + dmaoff + 2048, &sA[BUF][dmaoff + 2048]);               \
    gload16(ws + dmaoff + 4096, &sA[BUF][dmaoff + 4096]);               \
    gload16(ws + dmaoff + 6144, &sA[BUF][dmaoff + 6144]);               \
    f16x8 h0, h1;                                                       \
    { const float v = xv0; const f16 a = (f16)v; h0[0] = a; h1[0] = (f16)((v - (float)a) * 4096.f); } \
    { const float v = xv1; const f16 a = (f16)v; h0[1] = a; h1[1] = (f16)((v - (float)a) * 4096.f); } \
    { const float v = xv2; const f16 a = (f16)v; h0[2] = a; h1[2] = (f16)((v - (float)a) * 4096.f); } \
    { const float v = xv3; const f16 a = (f16)v; h0[3] = a; h1[3] = (f16)((v - (float)a) * 4096.f); } \
    { const float v = xv4; const f16 a = (f16)v; h0[4] = a; h1[4] = (f16)((v - (float)a) * 4096.f); } \
    { const float v = xv5; const f16 a = (f16)v; h0[5] = a; h1[5] = (f16)((v - (float)a) * 4096.f); } \
    { const float v = xv6; const f16 a = (f16)v; h0[6] = a; h1[6] = (f16)((v - (float)a) * 4096.f); } \
    { const float v = xv7; const f16 a = (f16)v; h0[7] = a; h1[7] = (f16)((v - (float)a) * 4096.f); } \
    *(f16x8*)&sB[BUF][xo0] = h0;                                        \
    *(f16x8*)&sB[BUF][xo1] = h1;                                        \
  }

#define COMPUTE(BUF)                                                    \
  {                                                                     \
    f16x8 b0[2], b1[2];                                                 \
    _Pragma("unroll")                                                   \
    for (int g = 0; g < 2; ++g) {                                       \
      b0[g] = *(const f16x8*)&sB[BUF][bO + g * 256];                    \
      b1[g] = *(const f16x8*)&sB[BUF][bO + g * 256 + 1024];             \
    }                                                                   \
    _Pragma("unroll")                                                   \
    for (int f = 0; f < 4; ++f) {                                       \
      const f16x8 a0 = *(const f16x8*)&sA[BUF][aO + f * 256];           \
      const f16x8 a1 = *(const f16x8*)&sA[BUF][aO + f * 256 + 2048];    \
      _Pragma("unroll")                                                 \
      for (int g = 0; g < 2; ++g) {                                     \
        acc0[f][g] = __builtin_amdgcn_mfma_f32_32x32x16_f16(a0, b0[g], acc0[f][g], 0, 0, 0); \
        acc1[f][g] = __builtin_amdgcn_mfma_f32_32x32x16_f16(a0, b1[g], acc1[f][g], 0, 0, 0); \
        acc1[f][g] = __builtin_amdgcn_mfma_f32_32x32x16_f16(a1, b0[g], acc1[f][g], 0, 0, 0); \
      }                                                                 \
    }                                                                   \
  }

  // prologue
  LOADX(0);
  STAGE(0, 0);
  LOADX(1);
  __syncthreads();

  int cur = 0;
  for (int it = 0; it < 128; ++it) {
    if (it < 127) STAGE(cur ^ 1, it + 1);
    if (it < 126) LOADX(it + 2);
    if (cur == 0) {
      COMPUTE(0);
    } else {
      COMPUTE(1);
    }
    __syncthreads();
    cur ^= 1;
  }

#undef LOADX
#undef STAGE
#undef COMPUTE

  // epilogue: z = acc0/64 + acc1/(64*4096), stored z[t][n]
  float* zb = z + (size_t)b * T_DIM * N_DIM;
  const float C0 = 0.015625f;
  const float C1 = 3.814697265625e-06f;
#pragma unroll
  for (int f = 0; f < 4; ++f)
#pragma unroll
    for (int g = 0; g < 2; ++g) {
      const int t = t0 + wt * 64 + g * 32 + l31;
      float* orow = zb + (size_t)t * N_DIM + n0 + wm * 128 + f * 32 + lhi * 4;
#pragma unroll
      for (int q = 0; q < 4; ++q) {
        float4 o;
        o.x = acc0[f][g][4 * q + 0] * C0 + acc1[f][g][4 * q + 0] * C1;
        o.y = acc0[f][g][4 * q + 1] * C0 + acc1[f][g][4 * q + 1] * C1;
        o.z = acc0[f][g][4 * q + 2] * C0 + acc1[f][g][4 * q + 2] * C1;
        o.w = acc0[f][g][4 * q + 3] * C0 + acc1[f][g][4 * q + 3] * C1;
        *(float4*)(orow + q * 8) = o;
      }
    }
}

// ---------------------------------------------------------------------------
// Kernel 2: sequential CUBA-KWTA recurrence, ballot-based spike count.
// ---------------------------------------------------------------------------
__global__ __launch_bounds__(256) void kwta_scan(const float* __restrict__ z,
                                                 const float* __restrict__ se,
                                                 unsigned int* __restrict__ bits) {
  const int b = blockIdx.x;
  const int tid = threadIdx.x;
  const int lane = tid & 63;
  const int wid = tid >> 6;

  float a = se[0];
  a = fminf(fmaxf(a, 0.f), 1.f);
  const float ap1 = 1.f + a;
  const float RB = 0.8046875f;  // TH*(N-2K)/N/WS exact

  __shared__ float part[2][4];

  const float* zb = z + (size_t)b * T_DIM * N_DIM + tid * 4;
  unsigned int* gb = bits + (size_t)b * 16 * N_DIM + tid * 4;

  float4 r0 = *(const float4*)(zb);
  float4 r1 = *(const float4*)(zb + 1 * N_DIM);
  float4 r2 = *(const float4*)(zb + 2 * N_DIM);
  float4 r3 = *(const float4*)(zb + 3 * N_DIM);
  float4 r4 = *(const float4*)(zb + 4 * N_DIM);
  float4 r5 = *(const float4*)(zb + 5 * N_DIM);
  float4 r6 = *(const float4*)(zb + 6 * N_DIM);
  float4 r7 = *(const float4*)(zb + 7 * N_DIM);

  float u0 = 0.f, u1 = 0.f, u2 = 0.f, u3 = 0.f;
  float v0 = 0.f, v1 = 0.f, v2 = 0.f, v3 = 0.f;
  float s0 = 0.f, s1 = 0.f, s2 = 0.f, s3 = 0.f;
  float S = 0.f;
  unsigned int c0 = 0, c1 = 0, c2 = 0, c3 = 0;

#define NEU(U, V, SV, C, ZV)                            \
  {                                                     \
    const float fb  = fmaf(ap1, SV, -S) + RB;           \
    const float inp = ZV + fb;                          \
    U = fmaf(0.75f, U, inp);                            \
    V = fmaf(0.9f, V, U);                               \
    const bool sp = (V >= 1.0f);                        \
    SV = sp ? 1.0f : 0.0f;                              \
    V  = sp ? 0.0f : V;                                 \
    C |= ((unsigned int)sp) << (t & 31);                \
    msum += __popcll(__ballot(sp));                     \
  }

#define STEP(KK, RQ)                                                    \
  {                                                                     \
    const int t = tbase + KK;                                           \
    const float4 z4 = RQ;                                               \
    int tn = t + 8;                                                     \
    if (tn > 511) tn = 511;                                             \
    RQ = *(const float4*)(zb + (size_t)tn * N_DIM);                     \
    int msum = 0;                                                       \
    NEU(u0, v0, s0, c0, z4.x)                                           \
    NEU(u1, v1, s1, c1, z4.y)                                           \
    NEU(u2, v2, s2, c2, z4.z)                                           \
    NEU(u3, v3, s3, c3, z4.w)                                           \
    if (lane == 0) part[t & 1][wid] = (float)msum;                      \
    __syncthreads();                                                    \
    S = (part[t & 1][0] + part[t & 1][1]) +                             \
        (part[t & 1][2] + part[t & 1][3]);                              \
    if ((t & 31) == 31) {                                               \
      *(uint4*)(gb + (size_t)(t >> 5) * N_DIM) =                        \
          make_uint4(c0, c1, c2, c3);                                   \
      c0 = c1 = c2 = c3 = 0;                                            \
    }                                                                   \
  }

  for (int tbase = 0; tbase < T_DIM; tbase += 8) {
    STEP(0, r0)
    STEP(1, r1)
    STEP(2, r2)
    STEP(3, r3)
    STEP(4, r4)
    STEP(5, r5)
    STEP(6, r6)
    STEP(7, r7)
  }
#undef STEP
#undef NEU
}

// ---------------------------------------------------------------------------
// Kernel 3: expand bits -> out[b][n][t] fp32 with 1-step delay shift.
// ---------------------------------------------------------------------------
__global__ __launch_bounds__(256) void expand_out(const unsigned int* __restrict__ bits,
                                                  float* __restrict__ out) {
  const int gid = blockIdx.x * 256 + threadIdx.x;
  const int l = gid & 63;
  const int row = gid >> 6;
  const int b = row >> 10;
  const int n = row & 1023;
  const unsigned int* r = bits + (size_t)b * 16 * N_DIM + n;

  unsigned int byte;
  if (l == 0) {
    byte = (r[0] << 1) & 0xFFu;
  } else {
    const int src = 8 * l - 1;
    const int w0 = src >> 5;
    const unsigned int lo = r[(size_t)w0 * N_DIM];
    const unsigned int hi = (w0 < 15) ? r[(size_t)(w0 + 1) * N_DIM] : 0u;
    const unsigned long long comb = ((unsigned long long)hi << 32) | (unsigned long long)lo;
    byte = (unsigned int)(comb >> (src & 31)) & 0xFFu;
  }

  float f[8];
#pragma unroll
  for (int k = 0; k < 8; ++k) f[k] = (float)((byte >> k) & 1u);

  float* o = out + ((size_t)row << 9) + (l << 3);
  *reinterpret_cast<float4*>(o)     = make_float4(f[0], f[1], f[2], f[3]);
  *reinterpret_cast<float4*>(o + 4) = make_float4(f[4], f[5], f[6], f[7]);
}

// ---------------------------------------------------------------------------
extern "C" void kernel_launch(void* const* d_in, const int* in_sizes, int n_in,
                              void* d_out, int out_size, void* d_ws, size_t ws_size,
                              hipStream_t stream) {
  const float* x  = (const float*)d_in[0];   // [64][2048][512]
  const float* w  = (const float*)d_in[1];   // [1024][2048]
  const float* se = (const float*)d_in[2];   // [1]
  float* out = (float*)d_out;                // [64][1024][512] fp32

  // wimg occupies d_ws[0, 8MB); bits reuses d_ws[0, 4MB) AFTER gemm (wimg dead)
  f16* wimg = (f16*)d_ws;
  unsigned int* bits = (unsigned int*)d_ws;

  presplit_w<<<1024, 256, 0, stream>>>(w, wimg);
  gemm_split<<<1024, 256, 0, stream>>>(x, wimg, out);
  kwta_scan<<<64, 256, 0, stream>>>(out, se, bits);
  expand_out<<<16384, 256, 0, stream>>>(bits, out);
}

// Round 8
// 2712.320 us; speedup vs baseline: 1.2168x; 1.0017x over previous
//
#include <hip/hip_runtime.h>

#define T_DIM 512
#define N_DIM 1024
#define K_DIM 2048

typedef _Float16 f16;
typedef _Float16 f16x8 __attribute__((ext_vector_type(8)));
typedef float f32x16 __attribute__((ext_vector_type(16)));
typedef __attribute__((address_space(1))) const unsigned int GU32;
typedef __attribute__((address_space(3))) unsigned int LU32;

__device__ __forceinline__ void gload16(const void* g, void* l) {
  __builtin_amdgcn_global_load_lds((GU32*)g, (LU32*)l, 16, 0, 0);
}

// ---------------------------------------------------------------------------
// Kernel 0: pre-split w into f16 {w0, w1} laid out as the GEMM's A-LDS image:
// wimg[nt(4)][k16(128)][ (lhi*2+c)*256 + row ] * 8 f16   (16 KB per (nt,k16))
//   v = 64*w ; w0 = f16(v) ; w1 = f16((v - w0) * 4096)
// ---------------------------------------------------------------------------
__global__ __launch_bounds__(256) void presplit_w(const float* __restrict__ w,
                                                  f16* __restrict__ wimg) {
  const int gid = blockIdx.x * 256 + threadIdx.x;  // 262144
  const int ko = gid >> 10;   // k-octet 0..255
  const int n = gid & 1023;
  const float* src = w + (size_t)n * K_DIM + (ko << 3);
  const float4 v0 = *(const float4*)src;
  const float4 v1 = *(const float4*)(src + 4);
  const float vv[8] = {v0.x, v0.y, v0.z, v0.w, v1.x, v1.y, v1.z, v1.w};
  f16x8 h0, h1;
#pragma unroll
  for (int q = 0; q < 8; ++q) {
    const float v = vv[q] * 64.f;
    const f16 a = (f16)v;
    h0[q] = a;
    h1[q] = (f16)((v - (float)a) * 4096.f);
  }
  const int nt = n >> 8, row = n & 255;
  const int k16 = ko >> 1, lhi = ko & 1;
  f16* blk = wimg + (size_t)(nt * 128 + k16) * 8192;
  *(f16x8*)&blk[(((lhi << 1) | 0) * 256 + row) * 8] = h0;
  *(f16x8*)&blk[(((lhi << 1) | 1) * 256 + row) * 8] = h1;
}

// ---------------------------------------------------------------------------
// Kernel 1: z[b][t][n] = sum_i w[n][i]*x[b][i][t]  (z into d_out, [B][T][N])
// Block 256(n) x 128(t), 4 waves (2n x 2t), wave tile 128x64 = (4,2) frags.
// 1 wave/SIMD (amdgpu_waves_per_eu(1,1)): 512-reg budget, demand ~340 -> no
// spill (R3-R5 spilled: acc128+arch~150 > 256 @2 waves/SIMD).
// A staged via global_load_lds from presplit wimg; x split in-register.
// acc0 += w0*x0 ; acc1 += w0*x1 + w1*x0 ; z = acc0/64 + acc1/(64*4096).
// R6 BUG FIX: sB was [2][2048]; layout needs 4 slots x 128 t x 8 f16 = 4096
// f16 per buffer -> OOB writes corrupted buffer 1 (absmax 1.0). Now [2][4096].
// ---------------------------------------------------------------------------
__global__ __launch_bounds__(256) __attribute__((amdgpu_waves_per_eu(1, 1)))
void gemm_split(const float* __restrict__ x,
                const f16* __restrict__ wimg,
                float* __restrict__ z) {
  const int p = blockIdx.x;
  const int lg = ((p & 7) << 7) | (p >> 3);  // bijective XCD swizzle (1024%8==0)
  const int nt = lg & 3;
  const int tt = (lg >> 2) & 3;
  const int b = lg >> 4;
  const int n0 = nt << 8, t0 = tt << 7;

  __shared__ f16 sA[2][8192];  // [(lhi*2+c)*256 + row]*8   16 KB/buf
  __shared__ f16 sB[2][4096];  // [(lhi*2+c)*128 + t]*8      8 KB/buf

  const int tid = threadIdx.x;
  const int lane = tid & 63;
  const int l31 = lane & 31, lhi = lane >> 5;
  const int wv = tid >> 6;   // 0..3
  const int wm = wv >> 1;    // 0..1 (n)
  const int wt = wv & 1;     // 0..1 (t)

  // x staging: tcol 0..127, kh 0..1 (8 k each)
  const int tcol = tid & 127, kh = tid >> 7;
  const float* pX = x + (size_t)b * (K_DIM * T_DIM) + (size_t)(kh * 8) * T_DIM + t0 + tcol;

  const f16* wbase = wimg + (size_t)nt * (128 * 8192);
  const int dmaoff = tid * 8;  // f16 elems; per-thread 4 chunks of 16B

  // fragment read offsets (f16 elems); +2048 elems switches comp c=0 -> c=1 (A)
  const int aO = ((lhi << 1) * 256 + wm * 128 + l31) * 8;
  const int bO = ((lhi << 1) * 128 + wt * 64 + l31) * 8;

  // x staging write offsets
  const int xo0 = (((kh << 1) | 0) * 128 + tcol) * 8;
  const int xo1 = (((kh << 1) | 1) * 128 + tcol) * 8;

  f32x16 acc0[4][2], acc1[4][2];
#pragma unroll
  for (int i = 0; i < 4; ++i)
#pragma unroll
    for (int j = 0; j < 2; ++j)
#pragma unroll
      for (int r = 0; r < 16; ++r) {
        acc0[i][j][r] = 0.f;
        acc1[i][j][r] = 0.f;
      }

  float xv0, xv1, xv2, xv3, xv4, xv5, xv6, xv7;

#define LOADX(IT)                                                       \
  {                                                                     \
    const float* px = pX + (size_t)((IT) * 16) * T_DIM;                 \
    xv0 = px[0];                                                        \
    xv1 = px[1 * T_DIM];                                                \
    xv2 = px[2 * T_DIM];                                                \
    xv3 = px[3 * T_DIM];                                                \
    xv4 = px[4 * T_DIM];                                                \
    xv5 = px[5 * T_DIM];                                                \
    xv6 = px[6 * T_DIM];                                                \
    xv7 = px[7 * T_DIM];                                                \
  }

#define STAGE(BUF, IT)                                                  \
  {                                                                     \
    const f16* ws = wbase + (size_t)(IT) * 8192;                        \
    gload16(ws + dmaoff, &sA[BUF][dmaoff]);                             \
    gload16(ws + dmaoff + 2048, &sA[BUF][dmaoff + 2048]);               \
    gload16(ws + dmaoff + 4096, &sA[BUF][dmaoff + 4096]);               \
    gload16(ws + dmaoff + 6144, &sA[BUF][dmaoff + 6144]);               \
    f16x8 h0, h1;                                                       \
    { const float v = xv0; const f16 a = (f16)v; h0[0] = a; h1[0] = (f16)((v - (float)a) * 4096.f); } \
    { const float v = xv1; const f16 a = (f16)v; h0[1] = a; h1[1] = (f16)((v - (float)a) * 4096.f); } \
    { const float v = xv2; const f16 a = (f16)v; h0[2] = a; h1[2] = (f16)((v - (float)a) * 4096.f); } \
    { const float v = xv3; const f16 a = (f16)v; h0[3] = a; h1[3] = (f16)((v - (float)a) * 4096.f); } \
    { const float v = xv4; const f16 a = (f16)v; h0[4] = a; h1[4] = (f16)((v - (float)a) * 4096.f); } \
    { const float v = xv5; const f16 a = (f16)v; h0[5] = a; h1[5] = (f16)((v - (float)a) * 4096.f); } \
    { const float v = xv6; const f16 a = (f16)v; h0[6] = a; h1[6] = (f16)((v - (float)a) * 4096.f); } \
    { const float v = xv7; const f16 a = (f16)v; h0[7] = a; h1[7] = (f16)((v - (float)a) * 4096.f); } \
    *(f16x8*)&sB[BUF][xo0] = h0;                                        \
    *(f16x8*)&sB[BUF][xo1] = h1;                                        \
  }

#define COMPUTE(BUF)                                                    \
  {                                                                     \
    f16x8 b0[2], b1[2];                                                 \
    _Pragma("unroll")                                                   \
    for (int g = 0; g < 2; ++g) {                                       \
      b0[g] = *(const f16x8*)&sB[BUF][bO + g * 256];                    \
      b1[g] = *(const f16x8*)&sB[BUF][bO + g * 256 + 1024];             \
    }                                                                   \
    _Pragma("unroll")                                                   \
    for (int f = 0; f < 4; ++f) {                                       \
      const f16x8 a0 = *(const f16x8*)&sA[BUF][aO + f * 256];           \
      const f16x8 a1 = *(const f16x8*)&sA[BUF][aO + f * 256 + 2048];    \
      _Pragma("unroll")                                                 \
      for (int g = 0; g < 2; ++g) {                                     \
        acc0[f][g] = __builtin_amdgcn_mfma_f32_32x32x16_f16(a0, b0[g], acc0[f][g], 0, 0, 0); \
        acc1[f][g] = __builtin_amdgcn_mfma_f32_32x32x16_f16(a0, b1[g], acc1[f][g], 0, 0, 0); \
        acc1[f][g] = __builtin_amdgcn_mfma_f32_32x32x16_f16(a1, b0[g], acc1[f][g], 0, 0, 0); \
      }                                                                 \
    }                                                                   \
  }

  // prologue
  LOADX(0);
  STAGE(0, 0);
  LOADX(1);
  __syncthreads();

  int cur = 0;
  for (int it = 0; it < 128; ++it) {
    if (it < 127) STAGE(cur ^ 1, it + 1);
    if (it < 126) LOADX(it + 2);
    if (cur == 0) {
      COMPUTE(0);
    } else {
      COMPUTE(1);
    }
    __syncthreads();
    cur ^= 1;
  }

#undef LOADX
#undef STAGE
#undef COMPUTE

  // epilogue: z = acc0/64 + acc1/(64*4096), stored z[t][n]
  float* zb = z + (size_t)b * T_DIM * N_DIM;
  const float C0 = 0.015625f;
  const float C1 = 3.814697265625e-06f;
#pragma unroll
  for (int f = 0; f < 4; ++f)
#pragma unroll
    for (int g = 0; g < 2; ++g) {
      const int t = t0 + wt * 64 + g * 32 + l31;
      float* orow = zb + (size_t)t * N_DIM + n0 + wm * 128 + f * 32 + lhi * 4;
#pragma unroll
      for (int q = 0; q < 4; ++q) {
        float4 o;
        o.x = acc0[f][g][4 * q + 0] * C0 + acc1[f][g][4 * q + 0] * C1;
        o.y = acc0[f][g][4 * q + 1] * C0 + acc1[f][g][4 * q + 1] * C1;
        o.z = acc0[f][g][4 * q + 2] * C0 + acc1[f][g][4 * q + 2] * C1;
        o.w = acc0[f][g][4 * q + 3] * C0 + acc1[f][g][4 * q + 3] * C1;
        *(float4*)(orow + q * 8) = o;
      }
    }
}

// ---------------------------------------------------------------------------
// Kernel 2: sequential CUBA-KWTA recurrence, ballot-based spike count.
// ---------------------------------------------------------------------------
__global__ __launch_bounds__(256) void kwta_scan(const float* __restrict__ z,
                                                 const float* __restrict__ se,
                                                 unsigned int* __restrict__ bits) {
  const int b = blockIdx.x;
  const int tid = threadIdx.x;
  const int lane = tid & 63;
  const int wid = tid >> 6;

  float a = se[0];
  a = fminf(fmaxf(a, 0.f), 1.f);
  const float ap1 = 1.f + a;
  const float RB = 0.8046875f;  // TH*(N-2K)/N/WS exact

  __shared__ float part[2][4];

  const float* zb = z + (size_t)b * T_DIM * N_DIM + tid * 4;
  unsigned int* gb = bits + (size_t)b * 16 * N_DIM + tid * 4;

  float4 r0 = *(const float4*)(zb);
  float4 r1 = *(const float4*)(zb + 1 * N_DIM);
  float4 r2 = *(const float4*)(zb + 2 * N_DIM);
  float4 r3 = *(const float4*)(zb + 3 * N_DIM);
  float4 r4 = *(const float4*)(zb + 4 * N_DIM);
  float4 r5 = *(const float4*)(zb + 5 * N_DIM);
  float4 r6 = *(const float4*)(zb + 6 * N_DIM);
  float4 r7 = *(const float4*)(zb + 7 * N_DIM);

  float u0 = 0.f, u1 = 0.f, u2 = 0.f, u3 = 0.f;
  float v0 = 0.f, v1 = 0.f, v2 = 0.f, v3 = 0.f;
  float s0 = 0.f, s1 = 0.f, s2 = 0.f, s3 = 0.f;
  float S = 0.f;
  unsigned int c0 = 0, c1 = 0, c2 = 0, c3 = 0;

#define NEU(U, V, SV, C, ZV)                            \
  {                                                     \
    const float fb  = fmaf(ap1, SV, -S) + RB;           \
    const float inp = ZV + fb;                          \
    U = fmaf(0.75f, U, inp);                            \
    V = fmaf(0.9f, V, U);                               \
    const bool sp = (V >= 1.0f);                        \
    SV = sp ? 1.0f : 0.0f;                              \
    V  = sp ? 0.0f : V;                                 \
    C |= ((unsigned int)sp) << (t & 31);                \
    msum += __popcll(__ballot(sp));                     \
  }

#define STEP(KK, RQ)                                                    \
  {                                                                     \
    const int t = tbase + KK;                                           \
    const float4 z4 = RQ;                                               \
    int tn = t + 8;                                                     \
    if (tn > 511) tn = 511;                                             \
    RQ = *(const float4*)(zb + (size_t)tn * N_DIM);                     \
    int msum = 0;                                                       \
    NEU(u0, v0, s0, c0, z4.x)                                           \
    NEU(u1, v1, s1, c1, z4.y)                                           \
    NEU(u2, v2, s2, c2, z4.z)                                           \
    NEU(u3, v3, s3, c3, z4.w)                                           \
    if (lane == 0) part[t & 1][wid] = (float)msum;                      \
    __syncthreads();                                                    \
    S = (part[t & 1][0] + part[t & 1][1]) +                             \
        (part[t & 1][2] + part[t & 1][3]);                              \
    if ((t & 31) == 31) {                                               \
      *(uint4*)(gb + (size_t)(t >> 5) * N_DIM) =                        \
          make_uint4(c0, c1, c2, c3);                                   \
      c0 = c1 = c2 = c3 = 0;                                            \
    }                                                                   \
  }

  for (int tbase = 0; tbase < T_DIM; tbase += 8) {
    STEP(0, r0)
    STEP(1, r1)
    STEP(2, r2)
    STEP(3, r3)
    STEP(4, r4)
    STEP(5, r5)
    STEP(6, r6)
    STEP(7, r7)
  }
#undef STEP
#undef NEU
}

// ---------------------------------------------------------------------------
// Kernel 3: expand bits -> out[b][n][t] fp32 with 1-step delay shift.
// ---------------------------------------------------------------------------
__global__ __launch_bounds__(256) void expand_out(const unsigned int* __restrict__ bits,
                                                  float* __restrict__ out) {
  const int gid = blockIdx.x * 256 + threadIdx.x;
  const int l = gid & 63;
  const int row = gid >> 6;
  const int b = row >> 10;
  const int n = row & 1023;
  const unsigned int* r = bits + (size_t)b * 16 * N_DIM + n;

  unsigned int byte;
  if (l == 0) {
    byte = (r[0] << 1) & 0xFFu;
  } else {
    const int src = 8 * l - 1;
    const int w0 = src >> 5;
    const unsigned int lo = r[(size_t)w0 * N_DIM];
    const unsigned int hi = (w0 < 15) ? r[(size_t)(w0 + 1) * N_DIM] : 0u;
    const unsigned long long comb = ((unsigned long long)hi << 32) | (unsigned long long)lo;
    byte = (unsigned int)(comb >> (src & 31)) & 0xFFu;
  }

  float f[8];
#pragma unroll
  for (int k = 0; k < 8; ++k) f[k] = (float)((byte >> k) & 1u);

  float* o = out + ((size_t)row << 9) + (l << 3);
  *reinterpret_cast<float4*>(o)     = make_float4(f[0], f[1], f[2], f[3]);
  *reinterpret_cast<float4*>(o + 4) = make_float4(f[4], f[5], f[6], f[7]);
}

// ---------------------------------------------------------------------------
extern "C" void kernel_launch(void* const* d_in, const int* in_sizes, int n_in,
                              void* d_out, int out_size, void* d_ws, size_t ws_size,
                              hipStream_t stream) {
  const float* x  = (const float*)d_in[0];   // [64][2048][512]
  const float* w  = (const float*)d_in[1];   // [1024][2048]
  const float* se = (const float*)d_in[2];   // [1]
  float* out = (float*)d_out;                // [64][1024][512] fp32

  // wimg occupies d_ws[0, 8MB); bits reuses d_ws[0, 4MB) AFTER gemm (wimg dead)
  f16* wimg = (f16*)d_ws;
  unsigned int* bits = (unsigned int*)d_ws;

  presplit_w<<<1024, 256, 0, stream>>>(w, wimg);
  gemm_split<<<1024, 256, 0, stream>>>(x, wimg, out);
  kwta_scan<<<64, 256, 0, stream>>>(out, se, bits);
  expand_out<<<16384, 256, 0, stream>>>(bits, out);
}

// Round 9
// 2408.917 us; speedup vs baseline: 1.3701x; 1.1260x over previous
//
#include <hip/hip_runtime.h>

#define T_DIM 512
#define N_DIM 1024
#define K_DIM 2048

typedef _Float16 f16;
typedef _Float16 f16x4 __attribute__((ext_vector_type(4)));
typedef _Float16 f16x8 __attribute__((ext_vector_type(8)));
typedef float f32x16 __attribute__((ext_vector_type(16)));
typedef __attribute__((address_space(1))) const unsigned int GU32;
typedef __attribute__((address_space(3))) unsigned int LU32;

__device__ __forceinline__ void gload16(const void* g, void* l) {
  __builtin_amdgcn_global_load_lds((GU32*)g, (LU32*)l, 16, 0, 0);
}

// ---------------------------------------------------------------------------
// Kernel 0: pre-split w into f16 {w0, w1} laid out as the GEMM's A-LDS image:
// wimg[nt(4)][k16(128)][ (lhi*2+c)*256 + row ] * 8 f16   (16 KB per (nt,k16))
//   v = 64*w ; w0 = f16(v) ; w1 = f16((v - w0) * 4096)
// ---------------------------------------------------------------------------
__global__ __launch_bounds__(256) void presplit_w(const float* __restrict__ w,
                                                  f16* __restrict__ wimg) {
  const int gid = blockIdx.x * 256 + threadIdx.x;  // 262144
  const int ko = gid >> 10;   // k-octet 0..255
  const int n = gid & 1023;
  const float* src = w + (size_t)n * K_DIM + (ko << 3);
  const float4 v0 = *(const float4*)src;
  const float4 v1 = *(const float4*)(src + 4);
  const float vv[8] = {v0.x, v0.y, v0.z, v0.w, v1.x, v1.y, v1.z, v1.w};
  f16x8 h0, h1;
#pragma unroll
  for (int q = 0; q < 8; ++q) {
    const float v = vv[q] * 64.f;
    const f16 a = (f16)v;
    h0[q] = a;
    h1[q] = (f16)((v - (float)a) * 4096.f);
  }
  const int nt = n >> 8, row = n & 255;
  const int k16 = ko >> 1, lhi = ko & 1;
  f16* blk = wimg + (size_t)(nt * 128 + k16) * 8192;
  *(f16x8*)&blk[(((lhi << 1) | 0) * 256 + row) * 8] = h0;
  *(f16x8*)&blk[(((lhi << 1) | 1) * 256 + row) * 8] = h1;
}

// ---------------------------------------------------------------------------
// Kernel 1: z[b][t][n] = sum_i w[n][i]*x[b][i][t]  (z into d_out, [B][T][N])
// Block 256(n) x 128(t), 8 waves (4n x 2t), wave tile 64x64 = (2,2) frags.
// acc = 128 f32/thread -> compiler AGPR-allocates (proven R2: VGPR=104).
// (4,2)'s 256-float acc pinned VGPR=256 and spilled 4.6 GB (R8 lesson).
// waves_per_eu(2,2): 256-reg unified budget/wave, demand ~230, 2 waves/SIMD.
// A staged via global_load_lds from presplit wimg; x split in-register.
// acc0 += w0*x0 ; acc1 += w0*x1 + w1*x0 ; z = acc0/64 + acc1/(64*4096).
// ---------------------------------------------------------------------------
__global__ __launch_bounds__(512) __attribute__((amdgpu_waves_per_eu(2, 2)))
void gemm_split(const float* __restrict__ x,
                const f16* __restrict__ wimg,
                float* __restrict__ z) {
  const int p = blockIdx.x;
  const int lg = ((p & 7) << 7) | (p >> 3);  // bijective XCD swizzle (1024%8==0)
  const int nt = lg & 3;
  const int tt = (lg >> 2) & 3;
  const int b = lg >> 4;
  const int n0 = nt << 8, t0 = tt << 7;

  __shared__ f16 sA[2][8192];  // [(kh*2+c)*256 + nrow]*8   16 KB/buf
  __shared__ f16 sB[2][4096];  // [(kh*2+c)*128 + t]*8       8 KB/buf

  const int tid = threadIdx.x;
  const int lane = tid & 63;
  const int l31 = lane & 31, lhi = lane >> 5;
  const int wv = tid >> 6;   // 0..7
  const int wm = wv >> 1;    // 0..3 (n)
  const int wt = wv & 1;     // 0..1 (t)

  // x staging: tcol 0..127, kq 0..3 (4 k each)
  const int tcol = tid & 127, kq = tid >> 7;
  const float* pX = x + (size_t)b * (K_DIM * T_DIM) + (size_t)(kq * 4) * T_DIM + t0 + tcol;

  const f16* wbase = wimg + (size_t)nt * (128 * 8192);
  const int dmaoff = tid * 8;  // f16 elems; 2 chunks of 16B per thread

  // fragment read offsets (f16 elems)
  const int aO = ((lhi << 1) * 256 + wm * 64 + l31) * 8;  // +2048: comp1, +f*256: frag
  const int bO = ((lhi << 1) * 128 + wt * 64 + l31) * 8;  // +1024: comp1, +g*256: frag

  // x staging write offsets: slot = (kh<<1)|c, kh = kq>>1; quarter = (kq&1)*4
  const int xo0 = ((((kq >> 1) << 1) | 0) * 128 + tcol) * 8 + (kq & 1) * 4;
  const int xo1 = ((((kq >> 1) << 1) | 1) * 128 + tcol) * 8 + (kq & 1) * 4;

  f32x16 acc0[2][2], acc1[2][2];
#pragma unroll
  for (int i = 0; i < 2; ++i)
#pragma unroll
    for (int j = 0; j < 2; ++j)
#pragma unroll
      for (int r = 0; r < 16; ++r) {
        acc0[i][j][r] = 0.f;
        acc1[i][j][r] = 0.f;
      }

  float xv0, xv1, xv2, xv3;

#define LOADX(IT)                                                       \
  {                                                                     \
    const float* px = pX + (size_t)((IT) * 16) * T_DIM;                 \
    xv0 = px[0];                                                        \
    xv1 = px[1 * T_DIM];                                                \
    xv2 = px[2 * T_DIM];                                                \
    xv3 = px[3 * T_DIM];                                                \
  }

#define STAGE(BUF, IT)                                                  \
  {                                                                     \
    const f16* ws = wbase + (size_t)(IT) * 8192;                        \
    gload16(ws + dmaoff, &sA[BUF][dmaoff]);                             \
    gload16(ws + dmaoff + 4096, &sA[BUF][dmaoff + 4096]);               \
    f16x4 h0, h1;                                                       \
    { const float v = xv0; const f16 a = (f16)v; h0[0] = a; h1[0] = (f16)((v - (float)a) * 4096.f); } \
    { const float v = xv1; const f16 a = (f16)v; h0[1] = a; h1[1] = (f16)((v - (float)a) * 4096.f); } \
    { const float v = xv2; const f16 a = (f16)v; h0[2] = a; h1[2] = (f16)((v - (float)a) * 4096.f); } \
    { const float v = xv3; const f16 a = (f16)v; h0[3] = a; h1[3] = (f16)((v - (float)a) * 4096.f); } \
    *(f16x4*)&sB[BUF][xo0] = h0;                                        \
    *(f16x4*)&sB[BUF][xo1] = h1;                                        \
  }

#define COMPUTE(BUF)                                                    \
  {                                                                     \
    f16x8 a0[2], a1[2], b0[2], b1[2];                                   \
    _Pragma("unroll")                                                   \
    for (int f = 0; f < 2; ++f) {                                       \
      a0[f] = *(const f16x8*)&sA[BUF][aO + f * 256];                    \
      a1[f] = *(const f16x8*)&sA[BUF][aO + f * 256 + 2048];             \
    }                                                                   \
    _Pragma("unroll")                                                   \
    for (int g = 0; g < 2; ++g) {                                       \
      b0[g] = *(const f16x8*)&sB[BUF][bO + g * 256];                    \
      b1[g] = *(const f16x8*)&sB[BUF][bO + g * 256 + 1024];             \
    }                                                                   \
    _Pragma("unroll")                                                   \
    for (int f = 0; f < 2; ++f)                                         \
      _Pragma("unroll")                                                 \
      for (int g = 0; g < 2; ++g) {                                     \
        acc0[f][g] = __builtin_amdgcn_mfma_f32_32x32x16_f16(a0[f], b0[g], acc0[f][g], 0, 0, 0); \
        acc1[f][g] = __builtin_amdgcn_mfma_f32_32x32x16_f16(a0[f], b1[g], acc1[f][g], 0, 0, 0); \
        acc1[f][g] = __builtin_amdgcn_mfma_f32_32x32x16_f16(a1[f], b0[g], acc1[f][g], 0, 0, 0); \
      }                                                                 \
  }

  // prologue
  LOADX(0);
  STAGE(0, 0);
  LOADX(1);
  __syncthreads();

  int cur = 0;
  for (int it = 0; it < 128; ++it) {
    if (it < 127) STAGE(cur ^ 1, it + 1);
    if (it < 126) LOADX(it + 2);
    if (cur == 0) {
      COMPUTE(0);
    } else {
      COMPUTE(1);
    }
    __syncthreads();
    cur ^= 1;
  }

#undef LOADX
#undef STAGE
#undef COMPUTE

  // epilogue: z = acc0/64 + acc1/(64*4096), stored z[t][n]
  float* zb = z + (size_t)b * T_DIM * N_DIM;
  const float C0 = 0.015625f;
  const float C1 = 3.814697265625e-06f;
#pragma unroll
  for (int f = 0; f < 2; ++f)
#pragma unroll
    for (int g = 0; g < 2; ++g) {
      const int t = t0 + wt * 64 + g * 32 + l31;
      float* orow = zb + (size_t)t * N_DIM + n0 + wm * 64 + f * 32 + lhi * 4;
#pragma unroll
      for (int q = 0; q < 4; ++q) {
        float4 o;
        o.x = acc0[f][g][4 * q + 0] * C0 + acc1[f][g][4 * q + 0] * C1;
        o.y = acc0[f][g][4 * q + 1] * C0 + acc1[f][g][4 * q + 1] * C1;
        o.z = acc0[f][g][4 * q + 2] * C0 + acc1[f][g][4 * q + 2] * C1;
        o.w = acc0[f][g][4 * q + 3] * C0 + acc1[f][g][4 * q + 3] * C1;
        *(float4*)(orow + q * 8) = o;
      }
    }
}

// ---------------------------------------------------------------------------
// Kernel 2: sequential CUBA-KWTA recurrence, ballot-based spike count.
// ---------------------------------------------------------------------------
__global__ __launch_bounds__(256) void kwta_scan(const float* __restrict__ z,
                                                 const float* __restrict__ se,
                                                 unsigned int* __restrict__ bits) {
  const int b = blockIdx.x;
  const int tid = threadIdx.x;
  const int lane = tid & 63;
  const int wid = tid >> 6;

  float a = se[0];
  a = fminf(fmaxf(a, 0.f), 1.f);
  const float ap1 = 1.f + a;
  const float RB = 0.8046875f;  // TH*(N-2K)/N/WS exact

  __shared__ float part[2][4];

  const float* zb = z + (size_t)b * T_DIM * N_DIM + tid * 4;
  unsigned int* gb = bits + (size_t)b * 16 * N_DIM + tid * 4;

  float4 r0 = *(const float4*)(zb);
  float4 r1 = *(const float4*)(zb + 1 * N_DIM);
  float4 r2 = *(const float4*)(zb + 2 * N_DIM);
  float4 r3 = *(const float4*)(zb + 3 * N_DIM);
  float4 r4 = *(const float4*)(zb + 4 * N_DIM);
  float4 r5 = *(const float4*)(zb + 5 * N_DIM);
  float4 r6 = *(const float4*)(zb + 6 * N_DIM);
  float4 r7 = *(const float4*)(zb + 7 * N_DIM);

  float u0 = 0.f, u1 = 0.f, u2 = 0.f, u3 = 0.f;
  float v0 = 0.f, v1 = 0.f, v2 = 0.f, v3 = 0.f;
  float s0 = 0.f, s1 = 0.f, s2 = 0.f, s3 = 0.f;
  float S = 0.f;
  unsigned int c0 = 0, c1 = 0, c2 = 0, c3 = 0;

#define NEU(U, V, SV, C, ZV)                            \
  {                                                     \
    const float fb  = fmaf(ap1, SV, -S) + RB;           \
    const float inp = ZV + fb;                          \
    U = fmaf(0.75f, U, inp);                            \
    V = fmaf(0.9f, V, U);                               \
    const bool sp = (V >= 1.0f);                        \
    SV = sp ? 1.0f : 0.0f;                              \
    V  = sp ? 0.0f : V;                                 \
    C |= ((unsigned int)sp) << (t & 31);                \
    msum += __popcll(__ballot(sp));                     \
  }

#define STEP(KK, RQ)                                                    \
  {                                                                     \
    const int t = tbase + KK;                                           \
    const float4 z4 = RQ;                                               \
    int tn = t + 8;                                                     \
    if (tn > 511) tn = 511;                                             \
    RQ = *(const float4*)(zb + (size_t)tn * N_DIM);                     \
    int msum = 0;                                                       \
    NEU(u0, v0, s0, c0, z4.x)                                           \
    NEU(u1, v1, s1, c1, z4.y)                                           \
    NEU(u2, v2, s2, c2, z4.z)                                           \
    NEU(u3, v3, s3, c3, z4.w)                                           \
    if (lane == 0) part[t & 1][wid] = (float)msum;                      \
    __syncthreads();                                                    \
    S = (part[t & 1][0] + part[t & 1][1]) +                             \
        (part[t & 1][2] + part[t & 1][3]);                              \
    if ((t & 31) == 31) {                                               \
      *(uint4*)(gb + (size_t)(t >> 5) * N_DIM) =                        \
          make_uint4(c0, c1, c2, c3);                                   \
      c0 = c1 = c2 = c3 = 0;                                            \
    }                                                                   \
  }

  for (int tbase = 0; tbase < T_DIM; tbase += 8) {
    STEP(0, r0)
    STEP(1, r1)
    STEP(2, r2)
    STEP(3, r3)
    STEP(4, r4)
    STEP(5, r5)
    STEP(6, r6)
    STEP(7, r7)
  }
#undef STEP
#undef NEU
}

// ---------------------------------------------------------------------------
// Kernel 3: expand bits -> out[b][n][t] fp32 with 1-step delay shift.
// ---------------------------------------------------------------------------
__global__ __launch_bounds__(256) void expand_out(const unsigned int* __restrict__ bits,
                                                  float* __restrict__ out) {
  const int gid = blockIdx.x * 256 + threadIdx.x;
  const int l = gid & 63;
  const int row = gid >> 6;
  const int b = row >> 10;
  const int n = row & 1023;
  const unsigned int* r = bits + (size_t)b * 16 * N_DIM + n;

  unsigned int byte;
  if (l == 0) {
    byte = (r[0] << 1) & 0xFFu;
  } else {
    const int src = 8 * l - 1;
    const int w0 = src >> 5;
    const unsigned int lo = r[(size_t)w0 * N_DIM];
    const unsigned int hi = (w0 < 15) ? r[(size_t)(w0 + 1) * N_DIM] : 0u;
    const unsigned long long comb = ((unsigned long long)hi << 32) | (unsigned long long)lo;
    byte = (unsigned int)(comb >> (src & 31)) & 0xFFu;
  }

  float f[8];
#pragma unroll
  for (int k = 0; k < 8; ++k) f[k] = (float)((byte >> k) & 1u);

  float* o = out + ((size_t)row << 9) + (l << 3);
  *reinterpret_cast<float4*>(o)     = make_float4(f[0], f[1], f[2], f[3]);
  *reinterpret_cast<float4*>(o + 4) = make_float4(f[4], f[5], f[6], f[7]);
}

// ---------------------------------------------------------------------------
extern "C" void kernel_launch(void* const* d_in, const int* in_sizes, int n_in,
                              void* d_out, int out_size, void* d_ws, size_t ws_size,
                              hipStream_t stream) {
  const float* x  = (const float*)d_in[0];   // [64][2048][512]
  const float* w  = (const float*)d_in[1];   // [1024][2048]
  const float* se = (const float*)d_in[2];   // [1]
  float* out = (float*)d_out;                // [64][1024][512] fp32

  // wimg occupies d_ws[0, 8MB); bits reuses d_ws[0, 4MB) AFTER gemm (wimg dead)
  f16* wimg = (f16*)d_ws;
  unsigned int* bits = (unsigned int*)d_ws;

  presplit_w<<<1024, 256, 0, stream>>>(w, wimg);
  gemm_split<<<1024, 512, 0, stream>>>(x, wimg, out);
  kwta_scan<<<64, 256, 0, stream>>>(out, se, bits);
  expand_out<<<16384, 256, 0, stream>>>(bits, out);
}

// Round 10
// 1564.227 us; speedup vs baseline: 2.1100x; 1.5400x over previous
//
#include <hip/hip_runtime.h>

#define T_DIM 512
#define N_DIM 1024
#define K_DIM 2048

typedef _Float16 f16;
typedef _Float16 f16x8 __attribute__((ext_vector_type(8)));
typedef float f32x16 __attribute__((ext_vector_type(16)));
typedef __attribute__((address_space(1))) const unsigned int GU32;
typedef __attribute__((address_space(3))) unsigned int LU32;

__device__ __forceinline__ void gload16(const void* g, void* l) {
  __builtin_amdgcn_global_load_lds((GU32*)g, (LU32*)l, 16, 0, 0);
}

// ---------------------------------------------------------------------------
// Kernel 0: pre-split w into f16 {w0,w1} laid out as the GEMM A-LDS image.
// wimg[nt(8)][k16(128)][slot(4)=(kh*2+c)][row(128)][8]   (8 KB per (nt,k16))
//   v = 64*w ; w0 = f16(v) ; w1 = f16((v - w0) * 4096)
// ---------------------------------------------------------------------------
__global__ __launch_bounds__(256) void presplit_w(const float* __restrict__ w,
                                                  f16* __restrict__ wimg) {
  const int gid = blockIdx.x * 256 + threadIdx.x;  // 262144 = 1024 n x 256 ko
  const int ko = gid >> 10;   // k-octet 0..255
  const int n = gid & 1023;
  const float* src = w + (size_t)n * K_DIM + (ko << 3);
  const float4 v0 = *(const float4*)src;
  const float4 v1 = *(const float4*)(src + 4);
  const float vv[8] = {v0.x, v0.y, v0.z, v0.w, v1.x, v1.y, v1.z, v1.w};
  f16x8 h0, h1;
#pragma unroll
  for (int q = 0; q < 8; ++q) {
    const float v = vv[q] * 64.f;
    const f16 a = (f16)v;
    h0[q] = a;
    h1[q] = (f16)((v - (float)a) * 4096.f);
  }
  const int nt = n >> 7, row = n & 127;
  const int k16 = ko >> 1, kh = ko & 1;
  f16* blk = wimg + (size_t)(nt * 128 + k16) * 4096;
  *(f16x8*)&blk[(((kh << 1) | 0) * 128 + row) * 8] = h0;
  *(f16x8*)&blk[(((kh << 1) | 1) * 128 + row) * 8] = h1;
}

// ---------------------------------------------------------------------------
// Kernel 1: z[b][t][n] = sum_i w[n][i]*x[b][i][t]  (z into d_out, [B][T][N])
// Block 128(n) x 128(t), 4 waves (2n x 2t), wave tile 64x64 = (2,2) frags.
// R2-proven register regime: acc = 128 f32/thread -> AGPR; arch ~95.
// waves_per_eu(2,2): 256-reg unified budget/wave, demand ~225 -> no spill.
// (R9: 512-thr shape needed ~273 > 256 -> 19-reg/iter spill, 5 GB writes.)
// A staged via global_load_lds from presplit wimg; x split in-register.
// acc0 += w0*x0 ; acc1 += w0*x1 + w1*x0 ; z = acc0/64 + acc1/(64*4096).
// XCD swizzle: 8 nt-siblings of one (b,tt) x-panel land on one XCD.
// ---------------------------------------------------------------------------
__global__ __launch_bounds__(256) __attribute__((amdgpu_waves_per_eu(2, 2)))
void gemm_split(const float* __restrict__ x,
                const f16* __restrict__ wimg,
                float* __restrict__ z) {
  // decode: p -> (c = XCD slot, nt, Ghi); G = Ghi*8+c -> (b,tt)
  const int p = blockIdx.x;
  const int c = p & 7;
  const int r = p >> 3;
  const int nt = r & 7;
  const int G = ((r >> 3) << 3) | c;   // 0..255
  const int b = G >> 2;
  const int tt = G & 3;
  const int n0 = nt << 7, t0 = tt << 7;

  __shared__ f16 sA[2][4096];  // [slot(4)][row(128)][8]  8 KB/buf
  __shared__ f16 sB[2][4096];  // [slot(4)][t(128)][8]    8 KB/buf

  const int tid = threadIdx.x;
  const int lane = tid & 63;
  const int l31 = lane & 31, lhi = lane >> 5;
  const int wv = tid >> 6;   // 0..3
  const int wm = wv >> 1;    // 0..1 (n)
  const int wt = wv & 1;     // 0..1 (t)

  // x staging: tcol 0..127, kh8 0..1 (8 k each)
  const int tcol = tid & 127, kh8 = tid >> 7;
  const float* pX = x + (size_t)b * (K_DIM * T_DIM) + (size_t)(kh8 * 8) * T_DIM + t0 + tcol;

  const f16* wbase = wimg + (size_t)nt * (128 * 4096);
  const int dmaoff = tid * 8;  // f16 elems; 2 chunks of 16B per thread

  // fragment read offsets (f16 elems): slot = (lhi<<1)|comp
  const int aoff = ((lhi << 1) * 128 + wm * 64 + l31) * 8;  // +1024: comp1, +f*256: frag
  const int boff = ((lhi << 1) * 128 + wt * 64 + l31) * 8;  // +1024: comp1, +g*256: frag

  // x staging write offsets (16B each)
  const int xo0 = (((kh8 << 1) | 0) * 128 + tcol) * 8;
  const int xo1 = (((kh8 << 1) | 1) * 128 + tcol) * 8;

  f32x16 acc0[2][2], acc1[2][2];
#pragma unroll
  for (int i = 0; i < 2; ++i)
#pragma unroll
    for (int j = 0; j < 2; ++j)
#pragma unroll
      for (int r2 = 0; r2 < 16; ++r2) {
        acc0[i][j][r2] = 0.f;
        acc1[i][j][r2] = 0.f;
      }

  float xv0, xv1, xv2, xv3, xv4, xv5, xv6, xv7;

#define LOADX(IT)                                                       \
  {                                                                     \
    const float* px = pX + (size_t)((IT) * 16) * T_DIM;                 \
    xv0 = px[0];                                                        \
    xv1 = px[1 * T_DIM];                                                \
    xv2 = px[2 * T_DIM];                                                \
    xv3 = px[3 * T_DIM];                                                \
    xv4 = px[4 * T_DIM];                                                \
    xv5 = px[5 * T_DIM];                                                \
    xv6 = px[6 * T_DIM];                                                \
    xv7 = px[7 * T_DIM];                                                \
  }

#define STAGE(BUF, IT)                                                  \
  {                                                                     \
    const f16* ws = wbase + (size_t)(IT) * 4096;                        \
    gload16(ws + dmaoff, &sA[BUF][dmaoff]);                             \
    gload16(ws + dmaoff + 2048, &sA[BUF][dmaoff + 2048]);               \
    f16x8 h0, h1;                                                       \
    { const float v = xv0; const f16 a = (f16)v; h0[0] = a; h1[0] = (f16)((v - (float)a) * 4096.f); } \
    { const float v = xv1; const f16 a = (f16)v; h0[1] = a; h1[1] = (f16)((v - (float)a) * 4096.f); } \
    { const float v = xv2; const f16 a = (f16)v; h0[2] = a; h1[2] = (f16)((v - (float)a) * 4096.f); } \
    { const float v = xv3; const f16 a = (f16)v; h0[3] = a; h1[3] = (f16)((v - (float)a) * 4096.f); } \
    { const float v = xv4; const f16 a = (f16)v; h0[4] = a; h1[4] = (f16)((v - (float)a) * 4096.f); } \
    { const float v = xv5; const f16 a = (f16)v; h0[5] = a; h1[5] = (f16)((v - (float)a) * 4096.f); } \
    { const float v = xv6; const f16 a = (f16)v; h0[6] = a; h1[6] = (f16)((v - (float)a) * 4096.f); } \
    { const float v = xv7; const f16 a = (f16)v; h0[7] = a; h1[7] = (f16)((v - (float)a) * 4096.f); } \
    *(f16x8*)&sB[BUF][xo0] = h0;                                        \
    *(f16x8*)&sB[BUF][xo1] = h1;                                        \
  }

#define COMPUTE(BUF)                                                    \
  {                                                                     \
    f16x8 a0[2], a1[2], b0[2], b1[2];                                   \
    _Pragma("unroll")                                                   \
    for (int f = 0; f < 2; ++f) {                                       \
      a0[f] = *(const f16x8*)&sA[BUF][aoff + f * 256];                  \
      a1[f] = *(const f16x8*)&sA[BUF][aoff + f * 256 + 1024];           \
    }                                                                   \
    _Pragma("unroll")                                                   \
    for (int g = 0; g < 2; ++g) {                                       \
      b0[g] = *(const f16x8*)&sB[BUF][boff + g * 256];                  \
      b1[g] = *(const f16x8*)&sB[BUF][boff + g * 256 + 1024];           \
    }                                                                   \
    _Pragma("unroll")                                                   \
    for (int f = 0; f < 2; ++f)                                         \
      _Pragma("unroll")                                                 \
      for (int g = 0; g < 2; ++g) {                                     \
        acc0[f][g] = __builtin_amdgcn_mfma_f32_32x32x16_f16(a0[f], b0[g], acc0[f][g], 0, 0, 0); \
        acc1[f][g] = __builtin_amdgcn_mfma_f32_32x32x16_f16(a0[f], b1[g], acc1[f][g], 0, 0, 0); \
        acc1[f][g] = __builtin_amdgcn_mfma_f32_32x32x16_f16(a1[f], b0[g], acc1[f][g], 0, 0, 0); \
      }                                                                 \
  }

  // prologue
  LOADX(0);
  STAGE(0, 0);
  LOADX(1);
  __syncthreads();

  int cur = 0;
  for (int it = 0; it < 128; ++it) {
    if (it < 127) STAGE(cur ^ 1, it + 1);
    if (it < 126) LOADX(it + 2);
    if (cur == 0) {
      COMPUTE(0);
    } else {
      COMPUTE(1);
    }
    __syncthreads();
    cur ^= 1;
  }

#undef LOADX
#undef STAGE
#undef COMPUTE

  // epilogue: z = acc0/64 + acc1/(64*4096), stored z[t][n]
  float* zb = z + (size_t)b * T_DIM * N_DIM;
  const float C0 = 0.015625f;
  const float C1 = 3.814697265625e-06f;
#pragma unroll
  for (int f = 0; f < 2; ++f)
#pragma unroll
    for (int g = 0; g < 2; ++g) {
      const int t = t0 + wt * 64 + g * 32 + l31;
      float* orow = zb + (size_t)t * N_DIM + n0 + wm * 64 + f * 32 + lhi * 4;
#pragma unroll
      for (int q = 0; q < 4; ++q) {
        float4 o;
        o.x = acc0[f][g][4 * q + 0] * C0 + acc1[f][g][4 * q + 0] * C1;
        o.y = acc0[f][g][4 * q + 1] * C0 + acc1[f][g][4 * q + 1] * C1;
        o.z = acc0[f][g][4 * q + 2] * C0 + acc1[f][g][4 * q + 2] * C1;
        o.w = acc0[f][g][4 * q + 3] * C0 + acc1[f][g][4 * q + 3] * C1;
        *(float4*)(orow + q * 8) = o;
      }
    }
}

// ---------------------------------------------------------------------------
// Kernel 2: sequential CUBA-KWTA recurrence, ballot-based spike count.
// ---------------------------------------------------------------------------
__global__ __launch_bounds__(256) void kwta_scan(const float* __restrict__ z,
                                                 const float* __restrict__ se,
                                                 unsigned int* __restrict__ bits) {
  const int b = blockIdx.x;
  const int tid = threadIdx.x;
  const int lane = tid & 63;
  const int wid = tid >> 6;

  float a = se[0];
  a = fminf(fmaxf(a, 0.f), 1.f);
  const float ap1 = 1.f + a;
  const float RB = 0.8046875f;  // TH*(N-2K)/N/WS exact

  __shared__ float part[2][4];

  const float* zb = z + (size_t)b * T_DIM * N_DIM + tid * 4;
  unsigned int* gb = bits + (size_t)b * 16 * N_DIM + tid * 4;

  float4 r0 = *(const float4*)(zb);
  float4 r1 = *(const float4*)(zb + 1 * N_DIM);
  float4 r2 = *(const float4*)(zb + 2 * N_DIM);
  float4 r3 = *(const float4*)(zb + 3 * N_DIM);
  float4 r4 = *(const float4*)(zb + 4 * N_DIM);
  float4 r5 = *(const float4*)(zb + 5 * N_DIM);
  float4 r6 = *(const float4*)(zb + 6 * N_DIM);
  float4 r7 = *(const float4*)(zb + 7 * N_DIM);

  float u0 = 0.f, u1 = 0.f, u2 = 0.f, u3 = 0.f;
  float v0 = 0.f, v1 = 0.f, v2 = 0.f, v3 = 0.f;
  float s0 = 0.f, s1 = 0.f, s2 = 0.f, s3 = 0.f;
  float S = 0.f;
  unsigned int c0 = 0, c1 = 0, c2 = 0, c3 = 0;

#define NEU(U, V, SV, C, ZV)                            \
  {                                                     \
    const float fb  = fmaf(ap1, SV, -S) + RB;           \
    const float inp = ZV + fb;                          \
    U = fmaf(0.75f, U, inp);                            \
    V = fmaf(0.9f, V, U);                               \
    const bool sp = (V >= 1.0f);                        \
    SV = sp ? 1.0f : 0.0f;                              \
    V  = sp ? 0.0f : V;                                 \
    C |= ((unsigned int)sp) << (t & 31);                \
    msum += __popcll(__ballot(sp));                     \
  }

#define STEP(KK, RQ)                                                    \
  {                                                                     \
    const int t = tbase + KK;                                           \
    const float4 z4 = RQ;                                               \
    int tn = t + 8;                                                     \
    if (tn > 511) tn = 511;                                             \
    RQ = *(const float4*)(zb + (size_t)tn * N_DIM);                     \
    int msum = 0;                                                       \
    NEU(u0, v0, s0, c0, z4.x)                                           \
    NEU(u1, v1, s1, c1, z4.y)                                           \
    NEU(u2, v2, s2, c2, z4.z)                                           \
    NEU(u3, v3, s3, c3, z4.w)                                           \
    if (lane == 0) part[t & 1][wid] = (float)msum;                      \
    __syncthreads();                                                    \
    S = (part[t & 1][0] + part[t & 1][1]) +                             \
        (part[t & 1][2] + part[t & 1][3]);                              \
    if ((t & 31) == 31) {                                               \
      *(uint4*)(gb + (size_t)(t >> 5) * N_DIM) =                        \
          make_uint4(c0, c1, c2, c3);                                   \
      c0 = c1 = c2 = c3 = 0;                                            \
    }                                                                   \
  }

  for (int tbase = 0; tbase < T_DIM; tbase += 8) {
    STEP(0, r0)
    STEP(1, r1)
    STEP(2, r2)
    STEP(3, r3)
    STEP(4, r4)
    STEP(5, r5)
    STEP(6, r6)
    STEP(7, r7)
  }
#undef STEP
#undef NEU
}

// ---------------------------------------------------------------------------
// Kernel 3: expand bits -> out[b][n][t] fp32 with 1-step delay shift.
// ---------------------------------------------------------------------------
__global__ __launch_bounds__(256) void expand_out(const unsigned int* __restrict__ bits,
                                                  float* __restrict__ out) {
  const int gid = blockIdx.x * 256 + threadIdx.x;
  const int l = gid & 63;
  const int row = gid >> 6;
  const int b = row >> 10;
  const int n = row & 1023;
  const unsigned int* r = bits + (size_t)b * 16 * N_DIM + n;

  unsigned int byte;
  if (l == 0) {
    byte = (r[0] << 1) & 0xFFu;
  } else {
    const int src = 8 * l - 1;
    const int w0 = src >> 5;
    const unsigned int lo = r[(size_t)w0 * N_DIM];
    const unsigned int hi = (w0 < 15) ? r[(size_t)(w0 + 1) * N_DIM] : 0u;
    const unsigned long long comb = ((unsigned long long)hi << 32) | (unsigned long long)lo;
    byte = (unsigned int)(comb >> (src & 31)) & 0xFFu;
  }

  float f[8];
#pragma unroll
  for (int k = 0; k < 8; ++k) f[k] = (float)((byte >> k) & 1u);

  float* o = out + ((size_t)row << 9) + (l << 3);
  *reinterpret_cast<float4*>(o)     = make_float4(f[0], f[1], f[2], f[3]);
  *reinterpret_cast<float4*>(o + 4) = make_float4(f[4], f[5], f[6], f[7]);
}

// ---------------------------------------------------------------------------
extern "C" void kernel_launch(void* const* d_in, const int* in_sizes, int n_in,
                              void* d_out, int out_size, void* d_ws, size_t ws_size,
                              hipStream_t stream) {
  const float* x  = (const float*)d_in[0];   // [64][2048][512]
  const float* w  = (const float*)d_in[1];   // [1024][2048]
  const float* se = (const float*)d_in[2];   // [1]
  float* out = (float*)d_out;                // [64][1024][512] fp32

  // wimg occupies d_ws[0, 8MB); bits reuses d_ws[0, 4MB) AFTER gemm (wimg dead)
  f16* wimg = (f16*)d_ws;
  unsigned int* bits = (unsigned int*)d_ws;

  presplit_w<<<1024, 256, 0, stream>>>(w, wimg);
  gemm_split<<<2048, 256, 0, stream>>>(x, wimg, out);
  kwta_scan<<<64, 256, 0, stream>>>(out, se, bits);
  expand_out<<<16384, 256, 0, stream>>>(bits, out);
}